// Round 10
// baseline (165.100 us; speedup 1.0000x reference)
//
#include <hip/hip_runtime.h>
#include <hip/hip_bf16.h>

#define IN_DIM 98304

typedef short bh8 __attribute__((ext_vector_type(8)));
typedef float f32x4 __attribute__((ext_vector_type(4)));
typedef unsigned short u16x8 __attribute__((ext_vector_type(8)));

__device__ __forceinline__ unsigned short f2bf(float f) {
  __hip_bfloat16 h = __float2bfloat16(f);
  return __builtin_bit_cast(unsigned short, h);
}

__device__ __forceinline__ void gload_lds16(const void* g, void* l) {
  __builtin_amdgcn_global_load_lds(
      (const __attribute__((address_space(1))) void*)g,
      (__attribute__((address_space(3))) void*)l, 16, 0, 0);
}

__device__ __forceinline__ void bfly(float2& a, float2& b, float wr, float wi) {
  float tr = wr * b.x - wi * b.y;
  float ti = wr * b.y + wi * b.x;
  b.x = a.x - tr; b.y = a.y - ti;
  a.x += tr; a.y += ti;
}

__device__ __forceinline__ float2 cmul(float2 a, float2 w) {
  return make_float2(a.x * w.x - a.y * w.y, a.x * w.y + a.y * w.x);
}

// 16-point FFT, input bit-reversed in v[], output natural order.
__device__ __forceinline__ void fft16(float2* v) {
  const float C8 = 0.70710678118654752f;
  const float C161 = 0.92387953251128674f, S161 = 0.38268343236508977f;
#pragma unroll
  for (int i = 0; i < 16; i += 2) bfly(v[i], v[i + 1], 1.f, 0.f);
#pragma unroll
  for (int i = 0; i < 16; i += 4) {
    bfly(v[i], v[i + 2], 1.f, 0.f);
    bfly(v[i + 1], v[i + 3], 0.f, -1.f);
  }
  {
    const float w8r[4] = {1.f, C8, 0.f, -C8};
    const float w8i[4] = {0.f, -C8, -1.f, -C8};
#pragma unroll
    for (int i = 0; i < 16; i += 8) {
#pragma unroll
      for (int j = 0; j < 4; ++j) bfly(v[i + j], v[i + j + 4], w8r[j], w8i[j]);
    }
  }
  {
    const float w16r[8] = {1.f, C161, C8, S161, 0.f, -S161, -C8, -C161};
    const float w16i[8] = {0.f, -S161, -C8, -C161, -1.f, -C161, -C8, -S161};
#pragma unroll
    for (int j = 0; j < 8; ++j) bfly(v[j], v[j + 8], w16r[j], w16i[j]);
  }
}

// 8-point FFT, input bit-reversed in v[], output natural order.
__device__ __forceinline__ void fft8(float2* v) {
  const float C8 = 0.70710678118654752f;
#pragma unroll
  for (int i = 0; i < 8; i += 2) bfly(v[i], v[i + 1], 1.f, 0.f);
#pragma unroll
  for (int i = 0; i < 8; i += 4) {
    bfly(v[i], v[i + 2], 1.f, 0.f);
    bfly(v[i + 1], v[i + 3], 0.f, -1.f);
  }
  bfly(v[0], v[4], 1.f, 0.f);
  bfly(v[1], v[5], C8, -C8);
  bfly(v[2], v[6], 0.f, -1.f);
  bfly(v[3], v[7], -C8, -C8);
}

// swizzled index into the [128][64] float2 tile (keeps bit0 -> float4 ok)
__device__ __forceinline__ int TIX(int r, int cc) {
  return (r << 6) + (cc ^ ((r & 7) << 1));
}

// ---------------------------------------------------------------------------
// Kernel 1: REAL-input 128x128 FFT2 + fftshift + amp/phase -> bf16 feats.
// (unchanged from R9 — within ~20% of its HBM floor)
// ---------------------------------------------------------------------------
__global__ __launch_bounds__(512, 4) void fft_feats_kernel(
    const float* __restrict__ img, unsigned short* __restrict__ feats) {
  __shared__ float2 tile[128 * 64];
  __shared__ float2 sm64[128];
  __shared__ float2 tw[128];
  const int tid = threadIdx.x;
  const int ch = blockIdx.x, b = blockIdx.y;
  const float* src = img + ((size_t)(b * 3 + ch) << 14);

  static const int BR4[16] = {0, 8, 4, 12, 2, 10, 6, 14, 1, 9, 5, 13, 3, 11, 7, 15};
  static const int BR3[8] = {0, 4, 2, 6, 1, 5, 3, 7};

  if (tid < 128) {
    float sv, cv;
    sincosf(-6.28318530717958647692f * (float)tid / 128.0f, &sv, &cv);
    tw[tid] = make_float2(cv, sv);
  }
#pragma unroll
  for (int it = 0; it < 8; ++it) {
    int i4 = it * 512 + tid;
    int r = i4 >> 5, c4 = i4 & 31;
    float4 x = *reinterpret_cast<const float4*>(src + (i4 << 2));
    *reinterpret_cast<float4*>(&tile[TIX(r, c4 * 2)]) = x;
  }
  __syncthreads();

  // ---- row pass stage 1: 64-pt FFT stage (8x8), unit (r, n2)
#pragma unroll
  for (int it = 0; it < 2; ++it) {
    int g = it * 512 + tid;
    int r = g >> 3, n2 = g & 7;
    float2 v[8];
#pragma unroll
    for (int j = 0; j < 8; ++j) v[j] = tile[TIX(r, (BR3[j] << 3) + n2)];
    fft8(v);
#pragma unroll
    for (int k1 = 1; k1 < 8; ++k1) v[k1] = cmul(v[k1], tw[2 * n2 * k1]);
#pragma unroll
    for (int k1 = 0; k1 < 8; ++k1) tile[TIX(r, (k1 << 3) + n2)] = v[k1];
  }
  __syncthreads();

  // ---- row pass stage 2
  {
    int r0 = tid >> 3, t8 = tid & 7;
    int r1 = r0 + 64;
    float2 ua[8], ub[8];
#pragma unroll
    for (int j = 0; j < 8; ++j) {
      ua[j] = tile[TIX(r0, (t8 << 3) + BR3[j])];
      ub[j] = tile[TIX(r1, (t8 << 3) + BR3[j])];
    }
    __syncthreads();
    fft8(ua);
    fft8(ub);
#pragma unroll
    for (int k2 = 0; k2 < 8; ++k2) {
      tile[TIX(r0, t8 + (k2 << 3))] = ua[k2];
      tile[TIX(r1, t8 + (k2 << 3))] = ub[k2];
    }
  }
  __syncthreads();

  // ---- untangle
#pragma unroll
  for (int it = 0; it < 8; ++it) {
    int g = it * 512 + tid;
    int r = g >> 5, k = g & 31;
    if (k == 0) {
      float2 z0 = tile[TIX(r, 0)];
      float2 z32 = tile[TIX(r, 32)];
      tile[TIX(r, 0)] = make_float2(z0.x + z0.y, 0.f);
      sm64[r] = make_float2(z0.x - z0.y, 0.f);
      tile[TIX(r, 32)] = make_float2(z32.x, -z32.y);
    } else {
      float2 zk = tile[TIX(r, k)];
      float2 zm = tile[TIX(r, 64 - k)];
      float2 ze = make_float2(0.5f * (zk.x + zm.x), 0.5f * (zk.y - zm.y));
      float2 zo = make_float2(0.5f * (zk.y + zm.y), -0.5f * (zk.x - zm.x));
      float2 t = cmul(zo, tw[k]);
      tile[TIX(r, k)] = make_float2(ze.x + t.x, ze.y + t.y);
      tile[TIX(r, 64 - k)] = make_float2(ze.x - t.x, -(ze.y - t.y));
    }
  }
  __syncthreads();

  // ---- col pass stage 1
  {
    int col = tid & 63, n2 = tid >> 6;
    float2 v[16];
#pragma unroll
    for (int j = 0; j < 16; ++j) v[j] = tile[TIX((BR4[j] << 3) + n2, col)];
    fft16(v);
#pragma unroll
    for (int k1 = 1; k1 < 16; ++k1) v[k1] = cmul(v[k1], tw[n2 * k1]);
#pragma unroll
    for (int k1 = 0; k1 < 16; ++k1) tile[TIX((k1 << 3) + n2, col)] = v[k1];
    if (tid < 8) {
      int m2 = tid;
      float2 w[16];
#pragma unroll
      for (int j = 0; j < 16; ++j) w[j] = sm64[(BR4[j] << 3) + m2];
      fft16(w);
#pragma unroll
      for (int k1 = 1; k1 < 16; ++k1) w[k1] = cmul(w[k1], tw[m2 * k1]);
#pragma unroll
      for (int k1 = 0; k1 < 16; ++k1) sm64[(k1 << 3) + m2] = w[k1];
    }
  }
  __syncthreads();

  // ---- col pass stage 2 + fftshift + amp/phase (+conjugate mirror writes)
  unsigned short* dst = feats + (size_t)b * IN_DIM + ch * 32768;
  {
    int col = tid & 63, t8 = tid >> 6;
    float2 u0[8], u1[8];
#pragma unroll
    for (int j = 0; j < 8; ++j) {
      u0[j] = tile[TIX((t8 << 3) + BR3[j], col)];
      u1[j] = tile[TIX(((t8 + 8) << 3) + BR3[j], col)];
    }
    fft8(u0);
    fft8(u1);
    const int ow = col + 64;
    const int owm = 64 - col;
#pragma unroll
    for (int k2 = 0; k2 < 8; ++k2) {
#pragma unroll
      for (int half = 0; half < 2; ++half) {
        float2 F = half ? u1[k2] : u0[k2];
        int kh = t8 + half * 8 + (k2 << 4);
        float amp = sqrtf(F.x * F.x + F.y * F.y);
        float ph = atan2f(F.y, F.x);
        int oh = kh ^ 64;
        dst[(oh << 7) + ow] = f2bf(amp);
        dst[16384 + (oh << 7) + ow] = f2bf(ph);
        if (col != 0) {
          int khm = (128 - kh) & 127;
          int ohm = khm ^ 64;
          dst[(ohm << 7) + owm] = f2bf(amp);
          dst[16384 + (ohm << 7) + owm] = f2bf(-ph);
        }
      }
    }
    if (tid < 8) {
      int t8t = tid;
      float2 e0[8], e1[8];
#pragma unroll
      for (int j = 0; j < 8; ++j) {
        e0[j] = sm64[(t8t << 3) + BR3[j]];
        e1[j] = sm64[((t8t + 8) << 3) + BR3[j]];
      }
      fft8(e0);
      fft8(e1);
#pragma unroll
      for (int k2 = 0; k2 < 8; ++k2) {
#pragma unroll
        for (int half = 0; half < 2; ++half) {
          float2 F = half ? e1[k2] : e0[k2];
          int kh = t8t + half * 8 + (k2 << 4);
          float amp = sqrtf(F.x * F.x + F.y * F.y);
          float ph = atan2f(F.y, F.x);
          int oh = kh ^ 64;
          dst[(oh << 7)] = f2bf(amp);
          dst[16384 + (oh << 7)] = f2bf(ph);
        }
      }
    }
  }
}

// ---------------------------------------------------------------------------
// Kernel 2: layer-1 GEMM. MT=256, NT=64, S=64 -> grid 512 = 2 blocks/CU,
// 256 threads (4 waves), LDS 72KB/block (2 fit). Same minimum-traffic
// property as R8 (A once, B once) but two independent barrier domains
// per CU overlap each other's stalls. A: global_load_lds depth-4 (4
// chunks/wave/iter); B: reg-staged fp32->bf16 once per tile, 2 LDS bufs.
// One s_barrier/iter. vmcnt: top=6 (allows loadB(k+1)+A(k+2); oldest-
// first retire forces A(k+1),A(k)); mid=4 before writeB (forces
// loadB(k+1)).
// ---------------------------------------------------------------------------
#define GS 64
#define GITERS 48

__global__ __launch_bounds__(256, 2) void gemm1_kernel(
    const unsigned short* __restrict__ feats, const float* __restrict__ W1,
    float* __restrict__ partial) {
  __shared__ __align__(16) unsigned short Asm[4][256 * 32];  // 4 x 16 KB
  __shared__ __align__(16) unsigned short Bsm[2][64 * 32];   // 2 x 4 KB
  const int tid = threadIdx.x;
  const int wv = tid >> 6, lane = tid & 63;

  // XCD decode: 8 blocks sharing ks (nt=0..7) land on one XCD -> A L2 reuse.
  const int f = blockIdx.x;
  const int xcd = f & 7, v = f >> 3;  // v: 0..63
  const int ks = xcd * 8 + (v & 7);   // 0..63
  const int nt = v >> 3;              // 0..7
  const int n0 = nt * 64;
  const size_t k0 = (size_t)ks * (GITERS * 32);

  // A staging: 16 chunks of 1KB; wave stages chunks 4wv..4wv+3.
  const int al_row = lane >> 2;
  const int al_k = (lane & 3) * 8;
  // B reg staging: thread -> row tid>>2 (0..63), quarter tid&3.
  const int brow = tid >> 2, bq = tid & 3;
  const float* bsrc = W1 + (size_t)(n0 + brow) * IN_DIM + k0 + bq * 8;

  auto stageA = [&](int buf, int it) {
    const size_t kb = k0 + (size_t)it * 32;
#pragma unroll
    for (int tl = 0; tl < 4; ++tl) {
      const int s = wv * 4 + tl;  // 0..15
      const unsigned short* ga =
          feats + (size_t)(s * 16 + al_row) * IN_DIM + kb + al_k;
      gload_lds16(ga, (char*)&Asm[buf][0] + s * 1024);
    }
  };

  float4 br0, br1;
  auto loadB = [&](int it) {
    const float* p = bsrc + (size_t)it * 32;
    br0 = *reinterpret_cast<const float4*>(p);
    br1 = *reinterpret_cast<const float4*>(p + 4);
  };
  auto writeB = [&](int buf) {
    u16x8 bw;
    bw[0] = f2bf(br0.x); bw[1] = f2bf(br0.y); bw[2] = f2bf(br0.z); bw[3] = f2bf(br0.w);
    bw[4] = f2bf(br1.x); bw[5] = f2bf(br1.y); bw[6] = f2bf(br1.z); bw[7] = f2bf(br1.w);
    *reinterpret_cast<u16x8*>(&Bsm[buf][brow * 32 + bq * 8]) = bw;
  };

  f32x4 acc[4][4];
#pragma unroll
  for (int i = 0; i < 4; ++i)
#pragma unroll
    for (int jj = 0; jj < 4; ++jj) acc[i][jj] = (f32x4){0.f, 0.f, 0.f, 0.f};

  // wave owns rows wv*64..wv*64+63, all 64 cols
  const int rm = lane & 15, hi = lane >> 4;

  // prologue
  stageA(0, 0);
  stageA(1, 1);
  stageA(2, 2);
  loadB(0);
  asm volatile("s_waitcnt vmcnt(0)" ::: "memory");
  writeB(0);
  loadB(1);

  for (int k = 0; k < GITERS; ++k) {
    const int rem = GITERS - 1 - k;
    if (rem >= 1) {
      asm volatile("s_waitcnt vmcnt(6) lgkmcnt(0)" ::: "memory");
    } else {
      asm volatile("s_waitcnt vmcnt(0) lgkmcnt(0)" ::: "memory");
    }
    __builtin_amdgcn_sched_barrier(0);
    __builtin_amdgcn_s_barrier();
    __builtin_amdgcn_sched_barrier(0);

    const int abuf = k & 3, bbuf = k & 1;
    bh8 afr[4], bfr[4];
#pragma unroll
    for (int i = 0; i < 4; ++i) {
      const int row = wv * 64 + i * 16 + rm;
      afr[i] = *reinterpret_cast<const bh8*>(&Asm[abuf][row * 32 + hi * 8]);
    }
#pragma unroll
    for (int jj = 0; jj < 4; ++jj) {
      const int row = jj * 16 + rm;
      bfr[jj] = *reinterpret_cast<const bh8*>(&Bsm[bbuf][row * 32 + hi * 8]);
    }
    __builtin_amdgcn_sched_barrier(0);

    if (rem >= 3) stageA((k + 3) & 3, k + 3);

    if (rem >= 1) {
      if (rem >= 3) {
        asm volatile("s_waitcnt vmcnt(4)" ::: "memory");
      } else {
        asm volatile("s_waitcnt vmcnt(0)" ::: "memory");
      }
      __builtin_amdgcn_sched_barrier(0);
      writeB((k + 1) & 1);
      if (rem >= 2) loadB(k + 2);
    }

    asm volatile("s_waitcnt lgkmcnt(1)" ::: "memory");
    __builtin_amdgcn_sched_barrier(0);

#pragma unroll
    for (int i = 0; i < 4; ++i)
#pragma unroll
      for (int jj = 0; jj < 4; ++jj)
        acc[i][jj] = __builtin_amdgcn_mfma_f32_16x16x32_bf16(
            afr[i], bfr[jj], acc[i][jj], 0, 0, 0);
  }

  // epilogue: C/D layout col=lane&15, row=(lane>>4)*4+reg (m89-verified)
  const int rg = lane >> 4;
  float* pbase = partial + ((size_t)ks << 17);
#pragma unroll
  for (int i = 0; i < 4; ++i) {
#pragma unroll
    for (int jj = 0; jj < 4; ++jj) {
      const int n = n0 + jj * 16 + rm;
#pragma unroll
      for (int r = 0; r < 4; ++r) {
        const int m = wv * 64 + i * 16 + rg * 4 + r;
        pbase[((size_t)m << 9) + n] = acc[i][jj][r];
      }
    }
  }
}

// ---------------------------------------------------------------------------
// Kernel 3: reduce split-K partials + bias + ReLU -> x1 [256][512] fp32
// ---------------------------------------------------------------------------
__global__ __launch_bounds__(256) void reduce1_kernel(
    const float* __restrict__ partial, const float* __restrict__ b1,
    float* __restrict__ x1, int S) {
  int i = blockIdx.x * 256 + threadIdx.x;
  float s = b1[i & 511];
  for (int p = 0; p < S; ++p) s += partial[((size_t)p << 17) + i];
  x1[i] = fmaxf(s, 0.0f);
}

// ---------------------------------------------------------------------------
// Kernel 4: x2 = relu(x1 @ W2^T + b2)
// ---------------------------------------------------------------------------
__global__ __launch_bounds__(256) void fc2_kernel(
    const float* __restrict__ x1, const float* __restrict__ W2,
    const float* __restrict__ b2, float* __restrict__ x2) {
  __shared__ float xs[512];
  int b = blockIdx.x, n = threadIdx.x;
  xs[n] = x1[b * 512 + n];
  xs[n + 256] = x1[b * 512 + 256 + n];
  __syncthreads();
  float acc = b2[n];
  const float* wr = W2 + (size_t)n * 512;
#pragma unroll 4
  for (int k = 0; k < 512; k += 4) {
    float4 w = *reinterpret_cast<const float4*>(wr + k);
    acc += xs[k] * w.x + xs[k + 1] * w.y + xs[k + 2] * w.z + xs[k + 3] * w.w;
  }
  x2[b * 256 + n] = fmaxf(acc, 0.0f);
}

// ---------------------------------------------------------------------------
// Kernel 5: out = x2 @ W3^T + b3
// ---------------------------------------------------------------------------
__global__ __launch_bounds__(128) void fc3_kernel(
    const float* __restrict__ x2, const float* __restrict__ W3,
    const float* __restrict__ b3, float* __restrict__ out) {
  __shared__ float xs[256];
  int b = blockIdx.x, n = threadIdx.x;
  xs[n] = x2[b * 256 + n];
  xs[n + 128] = x2[b * 256 + 128 + n];
  __syncthreads();
  float acc = b3[n];
  const float* wr = W3 + (size_t)n * 256;
#pragma unroll 4
  for (int k = 0; k < 256; k += 4) {
    float4 w = *reinterpret_cast<const float4*>(wr + k);
    acc += xs[k] * w.x + xs[k + 1] * w.y + xs[k + 2] * w.z + xs[k + 3] * w.w;
  }
  out[b * 128 + n] = acc;
}

extern "C" void kernel_launch(void* const* d_in, const int* in_sizes, int n_in,
                              void* d_out, int out_size, void* d_ws, size_t ws_size,
                              hipStream_t stream) {
  const float* img = (const float*)d_in[0];
  const float* W1 = (const float*)d_in[1];
  const float* b1 = (const float*)d_in[2];
  const float* W2 = (const float*)d_in[3];
  const float* b2 = (const float*)d_in[4];
  const float* W3 = (const float*)d_in[5];
  const float* b3 = (const float*)d_in[6];
  float* out = (float*)d_out;
  char* ws = (char*)d_ws;

  const size_t FEATS_B = 50331648ull;  // bf16 [256][98304]
  unsigned short* feats = (unsigned short*)ws;
  float* partial = (float*)(ws + FEATS_B);
  float* x1 = partial + (size_t)GS * 131072;
  float* x2 = x1 + 131072;

  hipLaunchKernelGGL(fft_feats_kernel, dim3(3, 256), dim3(512), 0, stream, img, feats);
  hipLaunchKernelGGL(gemm1_kernel, dim3(512), dim3(256), 0, stream, feats, W1, partial);
  hipLaunchKernelGGL(reduce1_kernel, dim3(512), dim3(256), 0, stream, partial, b1, x1, GS);
  hipLaunchKernelGGL(fc2_kernel, dim3(256), dim3(256), 0, stream, x1, W2, b2, x2);
  hipLaunchKernelGGL(fc3_kernel, dim3(256), dim3(128), 0, stream, x2, W3, b3, out);
}

// Round 11
// 138.050 us; speedup vs baseline: 1.1959x; 1.1959x over previous
//
#include <hip/hip_runtime.h>
#include <hip/hip_bf16.h>

#define IN_DIM 98304

typedef short bh8 __attribute__((ext_vector_type(8)));
typedef float f32x4 __attribute__((ext_vector_type(4)));
typedef unsigned short u16x8 __attribute__((ext_vector_type(8)));

__device__ __forceinline__ unsigned short f2bf(float f) {
  __hip_bfloat16 h = __float2bfloat16(f);
  return __builtin_bit_cast(unsigned short, h);
}

__device__ __forceinline__ void gload_lds16(const void* g, void* l) {
  __builtin_amdgcn_global_load_lds(
      (const __attribute__((address_space(1))) void*)g,
      (__attribute__((address_space(3))) void*)l, 16, 0, 0);
}

__device__ __forceinline__ void bfly(float2& a, float2& b, float wr, float wi) {
  float tr = wr * b.x - wi * b.y;
  float ti = wr * b.y + wi * b.x;
  b.x = a.x - tr; b.y = a.y - ti;
  a.x += tr; a.y += ti;
}

__device__ __forceinline__ float2 cmul(float2 a, float2 w) {
  return make_float2(a.x * w.x - a.y * w.y, a.x * w.y + a.y * w.x);
}

// 16-point FFT, input bit-reversed in v[], output natural order.
__device__ __forceinline__ void fft16(float2* v) {
  const float C8 = 0.70710678118654752f;
  const float C161 = 0.92387953251128674f, S161 = 0.38268343236508977f;
#pragma unroll
  for (int i = 0; i < 16; i += 2) bfly(v[i], v[i + 1], 1.f, 0.f);
#pragma unroll
  for (int i = 0; i < 16; i += 4) {
    bfly(v[i], v[i + 2], 1.f, 0.f);
    bfly(v[i + 1], v[i + 3], 0.f, -1.f);
  }
  {
    const float w8r[4] = {1.f, C8, 0.f, -C8};
    const float w8i[4] = {0.f, -C8, -1.f, -C8};
#pragma unroll
    for (int i = 0; i < 16; i += 8) {
#pragma unroll
      for (int j = 0; j < 4; ++j) bfly(v[i + j], v[i + j + 4], w8r[j], w8i[j]);
    }
  }
  {
    const float w16r[8] = {1.f, C161, C8, S161, 0.f, -S161, -C8, -C161};
    const float w16i[8] = {0.f, -S161, -C8, -C161, -1.f, -C161, -C8, -S161};
#pragma unroll
    for (int j = 0; j < 8; ++j) bfly(v[j], v[j + 8], w16r[j], w16i[j]);
  }
}

// 8-point FFT, input bit-reversed in v[], output natural order.
__device__ __forceinline__ void fft8(float2* v) {
  const float C8 = 0.70710678118654752f;
#pragma unroll
  for (int i = 0; i < 8; i += 2) bfly(v[i], v[i + 1], 1.f, 0.f);
#pragma unroll
  for (int i = 0; i < 8; i += 4) {
    bfly(v[i], v[i + 2], 1.f, 0.f);
    bfly(v[i + 1], v[i + 3], 0.f, -1.f);
  }
  bfly(v[0], v[4], 1.f, 0.f);
  bfly(v[1], v[5], C8, -C8);
  bfly(v[2], v[6], 0.f, -1.f);
  bfly(v[3], v[7], -C8, -C8);
}

// swizzled index into the [128][64] float2 tile (keeps bit0 -> float4 ok)
__device__ __forceinline__ int TIX(int r, int cc) {
  return (r << 6) + (cc ^ ((r & 7) << 1));
}

// ---------------------------------------------------------------------------
// Kernel 1: REAL-input 128x128 FFT2 + fftshift + amp/phase -> bf16 feats.
// (unchanged from R9 — within ~20% of its HBM floor)
// ---------------------------------------------------------------------------
__global__ __launch_bounds__(512, 4) void fft_feats_kernel(
    const float* __restrict__ img, unsigned short* __restrict__ feats) {
  __shared__ float2 tile[128 * 64];
  __shared__ float2 sm64[128];
  __shared__ float2 tw[128];
  const int tid = threadIdx.x;
  const int ch = blockIdx.x, b = blockIdx.y;
  const float* src = img + ((size_t)(b * 3 + ch) << 14);

  static const int BR4[16] = {0, 8, 4, 12, 2, 10, 6, 14, 1, 9, 5, 13, 3, 11, 7, 15};
  static const int BR3[8] = {0, 4, 2, 6, 1, 5, 3, 7};

  if (tid < 128) {
    float sv, cv;
    sincosf(-6.28318530717958647692f * (float)tid / 128.0f, &sv, &cv);
    tw[tid] = make_float2(cv, sv);
  }
#pragma unroll
  for (int it = 0; it < 8; ++it) {
    int i4 = it * 512 + tid;
    int r = i4 >> 5, c4 = i4 & 31;
    float4 x = *reinterpret_cast<const float4*>(src + (i4 << 2));
    *reinterpret_cast<float4*>(&tile[TIX(r, c4 * 2)]) = x;
  }
  __syncthreads();

  // ---- row pass stage 1: 64-pt FFT stage (8x8), unit (r, n2)
#pragma unroll
  for (int it = 0; it < 2; ++it) {
    int g = it * 512 + tid;
    int r = g >> 3, n2 = g & 7;
    float2 v[8];
#pragma unroll
    for (int j = 0; j < 8; ++j) v[j] = tile[TIX(r, (BR3[j] << 3) + n2)];
    fft8(v);
#pragma unroll
    for (int k1 = 1; k1 < 8; ++k1) v[k1] = cmul(v[k1], tw[2 * n2 * k1]);
#pragma unroll
    for (int k1 = 0; k1 < 8; ++k1) tile[TIX(r, (k1 << 3) + n2)] = v[k1];
  }
  __syncthreads();

  // ---- row pass stage 2
  {
    int r0 = tid >> 3, t8 = tid & 7;
    int r1 = r0 + 64;
    float2 ua[8], ub[8];
#pragma unroll
    for (int j = 0; j < 8; ++j) {
      ua[j] = tile[TIX(r0, (t8 << 3) + BR3[j])];
      ub[j] = tile[TIX(r1, (t8 << 3) + BR3[j])];
    }
    __syncthreads();
    fft8(ua);
    fft8(ub);
#pragma unroll
    for (int k2 = 0; k2 < 8; ++k2) {
      tile[TIX(r0, t8 + (k2 << 3))] = ua[k2];
      tile[TIX(r1, t8 + (k2 << 3))] = ub[k2];
    }
  }
  __syncthreads();

  // ---- untangle
#pragma unroll
  for (int it = 0; it < 8; ++it) {
    int g = it * 512 + tid;
    int r = g >> 5, k = g & 31;
    if (k == 0) {
      float2 z0 = tile[TIX(r, 0)];
      float2 z32 = tile[TIX(r, 32)];
      tile[TIX(r, 0)] = make_float2(z0.x + z0.y, 0.f);
      sm64[r] = make_float2(z0.x - z0.y, 0.f);
      tile[TIX(r, 32)] = make_float2(z32.x, -z32.y);
    } else {
      float2 zk = tile[TIX(r, k)];
      float2 zm = tile[TIX(r, 64 - k)];
      float2 ze = make_float2(0.5f * (zk.x + zm.x), 0.5f * (zk.y - zm.y));
      float2 zo = make_float2(0.5f * (zk.y + zm.y), -0.5f * (zk.x - zm.x));
      float2 t = cmul(zo, tw[k]);
      tile[TIX(r, k)] = make_float2(ze.x + t.x, ze.y + t.y);
      tile[TIX(r, 64 - k)] = make_float2(ze.x - t.x, -(ze.y - t.y));
    }
  }
  __syncthreads();

  // ---- col pass stage 1
  {
    int col = tid & 63, n2 = tid >> 6;
    float2 v[16];
#pragma unroll
    for (int j = 0; j < 16; ++j) v[j] = tile[TIX((BR4[j] << 3) + n2, col)];
    fft16(v);
#pragma unroll
    for (int k1 = 1; k1 < 16; ++k1) v[k1] = cmul(v[k1], tw[n2 * k1]);
#pragma unroll
    for (int k1 = 0; k1 < 16; ++k1) tile[TIX((k1 << 3) + n2, col)] = v[k1];
    if (tid < 8) {
      int m2 = tid;
      float2 w[16];
#pragma unroll
      for (int j = 0; j < 16; ++j) w[j] = sm64[(BR4[j] << 3) + m2];
      fft16(w);
#pragma unroll
      for (int k1 = 1; k1 < 16; ++k1) w[k1] = cmul(w[k1], tw[m2 * k1]);
#pragma unroll
      for (int k1 = 0; k1 < 16; ++k1) sm64[(k1 << 3) + m2] = w[k1];
    }
  }
  __syncthreads();

  // ---- col pass stage 2 + fftshift + amp/phase (+conjugate mirror writes)
  unsigned short* dst = feats + (size_t)b * IN_DIM + ch * 32768;
  {
    int col = tid & 63, t8 = tid >> 6;
    float2 u0[8], u1[8];
#pragma unroll
    for (int j = 0; j < 8; ++j) {
      u0[j] = tile[TIX((t8 << 3) + BR3[j], col)];
      u1[j] = tile[TIX(((t8 + 8) << 3) + BR3[j], col)];
    }
    fft8(u0);
    fft8(u1);
    const int ow = col + 64;
    const int owm = 64 - col;
#pragma unroll
    for (int k2 = 0; k2 < 8; ++k2) {
#pragma unroll
      for (int half = 0; half < 2; ++half) {
        float2 F = half ? u1[k2] : u0[k2];
        int kh = t8 + half * 8 + (k2 << 4);
        float amp = sqrtf(F.x * F.x + F.y * F.y);
        float ph = atan2f(F.y, F.x);
        int oh = kh ^ 64;
        dst[(oh << 7) + ow] = f2bf(amp);
        dst[16384 + (oh << 7) + ow] = f2bf(ph);
        if (col != 0) {
          int khm = (128 - kh) & 127;
          int ohm = khm ^ 64;
          dst[(ohm << 7) + owm] = f2bf(amp);
          dst[16384 + (ohm << 7) + owm] = f2bf(-ph);
        }
      }
    }
    if (tid < 8) {
      int t8t = tid;
      float2 e0[8], e1[8];
#pragma unroll
      for (int j = 0; j < 8; ++j) {
        e0[j] = sm64[(t8t << 3) + BR3[j]];
        e1[j] = sm64[((t8t + 8) << 3) + BR3[j]];
      }
      fft8(e0);
      fft8(e1);
#pragma unroll
      for (int k2 = 0; k2 < 8; ++k2) {
#pragma unroll
        for (int half = 0; half < 2; ++half) {
          float2 F = half ? e1[k2] : e0[k2];
          int kh = t8t + half * 8 + (k2 << 4);
          float amp = sqrtf(F.x * F.x + F.y * F.y);
          float ph = atan2f(F.y, F.x);
          int oh = kh ^ 64;
          dst[(oh << 7)] = f2bf(amp);
          dst[16384 + (oh << 7)] = f2bf(ph);
        }
      }
    }
  }
}

// ---------------------------------------------------------------------------
// Kernel 2: layer-1 GEMM — EXACT R9 kernel (best measured config).
// MT=256, NT=128, S=64 -> grid 256 = 1 block/CU, 512 threads. A via
// global_load_lds depth-4; B reg-staged fp32->bf16 once per tile;
// one s_barrier/iter, counted vmcnt.
// ---------------------------------------------------------------------------
#define GS 64
#define GITERS 48

__global__ __launch_bounds__(512, 2) void gemm1_kernel(
    const unsigned short* __restrict__ feats, const float* __restrict__ W1,
    float* __restrict__ partial) {
  __shared__ __align__(16) unsigned short Asm[4][256 * 32];
  __shared__ __align__(16) unsigned short Bsm[2][128 * 32];
  const int tid = threadIdx.x;
  const int wv = tid >> 6, lane = tid & 63;

  const int f = blockIdx.x;
  const int xcd = f & 7, v = f >> 3;
  const int ks = xcd * 8 + (v & 7);
  const int nt = v >> 3;
  const int n0 = nt * 128;
  const size_t k0 = (size_t)ks * (GITERS * 32);

  const int al_row = lane >> 2;
  const int al_k = (lane & 3) * 8;
  const int brow = tid >> 2, bq = tid & 3;
  const float* bsrc = W1 + (size_t)(n0 + brow) * IN_DIM + k0 + bq * 8;

  auto stageA = [&](int buf, int it) {
    const size_t kb = k0 + (size_t)it * 32;
#pragma unroll
    for (int tl = 0; tl < 2; ++tl) {
      const int s = wv * 2 + tl;
      const unsigned short* ga =
          feats + (size_t)(s * 16 + al_row) * IN_DIM + kb + al_k;
      gload_lds16(ga, (char*)&Asm[buf][0] + s * 1024);
    }
  };

  float4 br0, br1;
  auto loadB = [&](int it) {
    const float* p = bsrc + (size_t)it * 32;
    br0 = *reinterpret_cast<const float4*>(p);
    br1 = *reinterpret_cast<const float4*>(p + 4);
  };
  auto writeB = [&](int buf) {
    u16x8 bw;
    bw[0] = f2bf(br0.x); bw[1] = f2bf(br0.y); bw[2] = f2bf(br0.z); bw[3] = f2bf(br0.w);
    bw[4] = f2bf(br1.x); bw[5] = f2bf(br1.y); bw[6] = f2bf(br1.z); bw[7] = f2bf(br1.w);
    *reinterpret_cast<u16x8*>(&Bsm[buf][brow * 32 + bq * 8]) = bw;
  };

  f32x4 acc[4][4];
#pragma unroll
  for (int i = 0; i < 4; ++i)
#pragma unroll
    for (int jj = 0; jj < 4; ++jj) acc[i][jj] = (f32x4){0.f, 0.f, 0.f, 0.f};

  const int mr = wv & 3;
  const int nc = wv >> 2;
  const int rm = lane & 15, hi = lane >> 4;

  stageA(0, 0);
  stageA(1, 1);
  stageA(2, 2);
  loadB(0);
  asm volatile("s_waitcnt vmcnt(0)" ::: "memory");
  writeB(0);
  loadB(1);

  for (int k = 0; k < GITERS; ++k) {
    const int rem = GITERS - 1 - k;
    if (rem >= 1) {
      asm volatile("s_waitcnt vmcnt(4) lgkmcnt(0)" ::: "memory");
    } else {
      asm volatile("s_waitcnt vmcnt(0) lgkmcnt(0)" ::: "memory");
    }
    __builtin_amdgcn_sched_barrier(0);
    __builtin_amdgcn_s_barrier();
    __builtin_amdgcn_sched_barrier(0);

    const int abuf = k & 3, bbuf = k & 1;
    bh8 afr[4], bfr[4];
#pragma unroll
    for (int i = 0; i < 4; ++i) {
      const int row = mr * 64 + i * 16 + rm;
      afr[i] = *reinterpret_cast<const bh8*>(&Asm[abuf][row * 32 + hi * 8]);
    }
#pragma unroll
    for (int jj = 0; jj < 4; ++jj) {
      const int row = nc * 64 + jj * 16 + rm;
      bfr[jj] = *reinterpret_cast<const bh8*>(&Bsm[bbuf][row * 32 + hi * 8]);
    }
    __builtin_amdgcn_sched_barrier(0);

    if (rem >= 3) stageA((k + 3) & 3, k + 3);

    if (rem >= 1) {
      if (rem >= 3) {
        asm volatile("s_waitcnt vmcnt(2)" ::: "memory");
      } else {
        asm volatile("s_waitcnt vmcnt(0)" ::: "memory");
      }
      __builtin_amdgcn_sched_barrier(0);
      writeB((k + 1) & 1);
      if (rem >= 2) loadB(k + 2);
    }

    asm volatile("s_waitcnt lgkmcnt(1)" ::: "memory");
    __builtin_amdgcn_sched_barrier(0);

#pragma unroll
    for (int i = 0; i < 4; ++i)
#pragma unroll
      for (int jj = 0; jj < 4; ++jj)
        acc[i][jj] = __builtin_amdgcn_mfma_f32_16x16x32_bf16(
            afr[i], bfr[jj], acc[i][jj], 0, 0, 0);
  }

  const int rg = lane >> 4;
  float* pbase = partial + ((size_t)ks << 17);
#pragma unroll
  for (int i = 0; i < 4; ++i) {
#pragma unroll
    for (int jj = 0; jj < 4; ++jj) {
      const int n = n0 + nc * 64 + jj * 16 + rm;
#pragma unroll
      for (int r = 0; r < 4; ++r) {
        const int m = mr * 64 + i * 16 + rg * 4 + r;
        pbase[((size_t)m << 9) + n] = acc[i][jj][r];
      }
    }
  }
}

// ---------------------------------------------------------------------------
// Kernel 3: FUSED tail. All post-gemm work is row-local in b:
// block b: x1[b] = relu(sum_p partial[p][b] + b1)  (LDS)
//          x2[b] = relu(x1[b] @ W2^T + b2)         (LDS)
//          out[b] = x2[b] @ W3^T + b3
// One kernel instead of three: saves 2 launch gaps + x1/x2 HBM round trips.
// ---------------------------------------------------------------------------
__global__ __launch_bounds__(256) void tail_kernel(
    const float* __restrict__ partial, const float* __restrict__ b1,
    const float* __restrict__ W2, const float* __restrict__ b2,
    const float* __restrict__ W3, const float* __restrict__ b3,
    float* __restrict__ out) {
  __shared__ float x1s[512];
  __shared__ float x2s[256];
  const int b = blockIdx.x, n = threadIdx.x;

  // phase 1: reduce split-K partials for row b (coalesced: lanes->cols)
  {
    float s0 = b1[n], s1 = b1[n + 256];
    const float* pb = partial + ((size_t)b << 9);
#pragma unroll 8
    for (int p = 0; p < GS; ++p) {
      const float* pp = pb + ((size_t)p << 17);
      s0 += pp[n];
      s1 += pp[n + 256];
    }
    x1s[n] = fmaxf(s0, 0.f);
    x1s[n + 256] = fmaxf(s1, 0.f);
  }
  __syncthreads();

  // phase 2: x2 = relu(x1 @ W2^T + b2)
  {
    float acc = b2[n];
    const float* wr = W2 + (size_t)n * 512;
#pragma unroll 4
    for (int k = 0; k < 512; k += 4) {
      float4 w = *reinterpret_cast<const float4*>(wr + k);
      acc += x1s[k] * w.x + x1s[k + 1] * w.y + x1s[k + 2] * w.z + x1s[k + 3] * w.w;
    }
    x2s[n] = fmaxf(acc, 0.f);
  }
  __syncthreads();

  // phase 3: out = x2 @ W3^T + b3
  if (n < 128) {
    float acc = b3[n];
    const float* wr = W3 + (size_t)n * 256;
#pragma unroll 4
    for (int k = 0; k < 256; k += 4) {
      float4 w = *reinterpret_cast<const float4*>(wr + k);
      acc += x2s[k] * w.x + x2s[k + 1] * w.y + x2s[k + 2] * w.z + x2s[k + 3] * w.w;
    }
    out[b * 128 + n] = acc;
  }
}

extern "C" void kernel_launch(void* const* d_in, const int* in_sizes, int n_in,
                              void* d_out, int out_size, void* d_ws, size_t ws_size,
                              hipStream_t stream) {
  const float* img = (const float*)d_in[0];
  const float* W1 = (const float*)d_in[1];
  const float* b1 = (const float*)d_in[2];
  const float* W2 = (const float*)d_in[3];
  const float* b2 = (const float*)d_in[4];
  const float* W3 = (const float*)d_in[5];
  const float* b3 = (const float*)d_in[6];
  float* out = (float*)d_out;
  char* ws = (char*)d_ws;

  const size_t FEATS_B = 50331648ull;  // bf16 [256][98304]
  unsigned short* feats = (unsigned short*)ws;
  float* partial = (float*)(ws + FEATS_B);

  hipLaunchKernelGGL(fft_feats_kernel, dim3(3, 256), dim3(512), 0, stream, img, feats);
  hipLaunchKernelGGL(gemm1_kernel, dim3(256), dim3(512), 0, stream, feats, W1, partial);
  hipLaunchKernelGGL(tail_kernel, dim3(256), dim3(256), 0, stream,
                     partial, b1, W2, b2, W3, b3, out);
}

// Round 12
// 131.709 us; speedup vs baseline: 1.2535x; 1.0481x over previous
//
#include <hip/hip_runtime.h>
#include <hip/hip_bf16.h>

#define IN_DIM 98304

typedef short bh8 __attribute__((ext_vector_type(8)));
typedef float f32x4 __attribute__((ext_vector_type(4)));
typedef unsigned short u16x8 __attribute__((ext_vector_type(8)));

__device__ __forceinline__ unsigned short f2bf(float f) {
  __hip_bfloat16 h = __float2bfloat16(f);
  return __builtin_bit_cast(unsigned short, h);
}

__device__ __forceinline__ void gload_lds16(const void* g, void* l) {
  __builtin_amdgcn_global_load_lds(
      (const __attribute__((address_space(1))) void*)g,
      (__attribute__((address_space(3))) void*)l, 16, 0, 0);
}

__device__ __forceinline__ void bfly(float2& a, float2& b, float wr, float wi) {
  float tr = wr * b.x - wi * b.y;
  float ti = wr * b.y + wi * b.x;
  b.x = a.x - tr; b.y = a.y - ti;
  a.x += tr; a.y += ti;
}

__device__ __forceinline__ float2 cmul(float2 a, float2 w) {
  return make_float2(a.x * w.x - a.y * w.y, a.x * w.y + a.y * w.x);
}

// 16-point FFT, input bit-reversed in v[], output natural order.
__device__ __forceinline__ void fft16(float2* v) {
  const float C8 = 0.70710678118654752f;
  const float C161 = 0.92387953251128674f, S161 = 0.38268343236508977f;
#pragma unroll
  for (int i = 0; i < 16; i += 2) bfly(v[i], v[i + 1], 1.f, 0.f);
#pragma unroll
  for (int i = 0; i < 16; i += 4) {
    bfly(v[i], v[i + 2], 1.f, 0.f);
    bfly(v[i + 1], v[i + 3], 0.f, -1.f);
  }
  {
    const float w8r[4] = {1.f, C8, 0.f, -C8};
    const float w8i[4] = {0.f, -C8, -1.f, -C8};
#pragma unroll
    for (int i = 0; i < 16; i += 8) {
#pragma unroll
      for (int j = 0; j < 4; ++j) bfly(v[i + j], v[i + j + 4], w8r[j], w8i[j]);
    }
  }
  {
    const float w16r[8] = {1.f, C161, C8, S161, 0.f, -S161, -C8, -C161};
    const float w16i[8] = {0.f, -S161, -C8, -C161, -1.f, -C161, -C8, -S161};
#pragma unroll
    for (int j = 0; j < 8; ++j) bfly(v[j], v[j + 8], w16r[j], w16i[j]);
  }
}

// 8-point FFT, input bit-reversed in v[], output natural order.
__device__ __forceinline__ void fft8(float2* v) {
  const float C8 = 0.70710678118654752f;
#pragma unroll
  for (int i = 0; i < 8; i += 2) bfly(v[i], v[i + 1], 1.f, 0.f);
#pragma unroll
  for (int i = 0; i < 8; i += 4) {
    bfly(v[i], v[i + 2], 1.f, 0.f);
    bfly(v[i + 1], v[i + 3], 0.f, -1.f);
  }
  bfly(v[0], v[4], 1.f, 0.f);
  bfly(v[1], v[5], C8, -C8);
  bfly(v[2], v[6], 0.f, -1.f);
  bfly(v[3], v[7], -C8, -C8);
}

// swizzled index into the [128][64] float2 tile (keeps bit0 -> float4 ok)
__device__ __forceinline__ int TIX(int r, int cc) {
  return (r << 6) + (cc ^ ((r & 7) << 1));
}

// ---------------------------------------------------------------------------
// Kernel 1: REAL-input 128x128 FFT2 + fftshift + amp/phase -> bf16 feats.
// (unchanged from R9 — within ~20% of its HBM floor)
// ---------------------------------------------------------------------------
__global__ __launch_bounds__(512, 4) void fft_feats_kernel(
    const float* __restrict__ img, unsigned short* __restrict__ feats) {
  __shared__ float2 tile[128 * 64];
  __shared__ float2 sm64[128];
  __shared__ float2 tw[128];
  const int tid = threadIdx.x;
  const int ch = blockIdx.x, b = blockIdx.y;
  const float* src = img + ((size_t)(b * 3 + ch) << 14);

  static const int BR4[16] = {0, 8, 4, 12, 2, 10, 6, 14, 1, 9, 5, 13, 3, 11, 7, 15};
  static const int BR3[8] = {0, 4, 2, 6, 1, 5, 3, 7};

  if (tid < 128) {
    float sv, cv;
    sincosf(-6.28318530717958647692f * (float)tid / 128.0f, &sv, &cv);
    tw[tid] = make_float2(cv, sv);
  }
#pragma unroll
  for (int it = 0; it < 8; ++it) {
    int i4 = it * 512 + tid;
    int r = i4 >> 5, c4 = i4 & 31;
    float4 x = *reinterpret_cast<const float4*>(src + (i4 << 2));
    *reinterpret_cast<float4*>(&tile[TIX(r, c4 * 2)]) = x;
  }
  __syncthreads();

  // ---- row pass stage 1: 64-pt FFT stage (8x8), unit (r, n2)
#pragma unroll
  for (int it = 0; it < 2; ++it) {
    int g = it * 512 + tid;
    int r = g >> 3, n2 = g & 7;
    float2 v[8];
#pragma unroll
    for (int j = 0; j < 8; ++j) v[j] = tile[TIX(r, (BR3[j] << 3) + n2)];
    fft8(v);
#pragma unroll
    for (int k1 = 1; k1 < 8; ++k1) v[k1] = cmul(v[k1], tw[2 * n2 * k1]);
#pragma unroll
    for (int k1 = 0; k1 < 8; ++k1) tile[TIX(r, (k1 << 3) + n2)] = v[k1];
  }
  __syncthreads();

  // ---- row pass stage 2
  {
    int r0 = tid >> 3, t8 = tid & 7;
    int r1 = r0 + 64;
    float2 ua[8], ub[8];
#pragma unroll
    for (int j = 0; j < 8; ++j) {
      ua[j] = tile[TIX(r0, (t8 << 3) + BR3[j])];
      ub[j] = tile[TIX(r1, (t8 << 3) + BR3[j])];
    }
    __syncthreads();
    fft8(ua);
    fft8(ub);
#pragma unroll
    for (int k2 = 0; k2 < 8; ++k2) {
      tile[TIX(r0, t8 + (k2 << 3))] = ua[k2];
      tile[TIX(r1, t8 + (k2 << 3))] = ub[k2];
    }
  }
  __syncthreads();

  // ---- untangle
#pragma unroll
  for (int it = 0; it < 8; ++it) {
    int g = it * 512 + tid;
    int r = g >> 5, k = g & 31;
    if (k == 0) {
      float2 z0 = tile[TIX(r, 0)];
      float2 z32 = tile[TIX(r, 32)];
      tile[TIX(r, 0)] = make_float2(z0.x + z0.y, 0.f);
      sm64[r] = make_float2(z0.x - z0.y, 0.f);
      tile[TIX(r, 32)] = make_float2(z32.x, -z32.y);
    } else {
      float2 zk = tile[TIX(r, k)];
      float2 zm = tile[TIX(r, 64 - k)];
      float2 ze = make_float2(0.5f * (zk.x + zm.x), 0.5f * (zk.y - zm.y));
      float2 zo = make_float2(0.5f * (zk.y + zm.y), -0.5f * (zk.x - zm.x));
      float2 t = cmul(zo, tw[k]);
      tile[TIX(r, k)] = make_float2(ze.x + t.x, ze.y + t.y);
      tile[TIX(r, 64 - k)] = make_float2(ze.x - t.x, -(ze.y - t.y));
    }
  }
  __syncthreads();

  // ---- col pass stage 1
  {
    int col = tid & 63, n2 = tid >> 6;
    float2 v[16];
#pragma unroll
    for (int j = 0; j < 16; ++j) v[j] = tile[TIX((BR4[j] << 3) + n2, col)];
    fft16(v);
#pragma unroll
    for (int k1 = 1; k1 < 16; ++k1) v[k1] = cmul(v[k1], tw[n2 * k1]);
#pragma unroll
    for (int k1 = 0; k1 < 16; ++k1) tile[TIX((k1 << 3) + n2, col)] = v[k1];
    if (tid < 8) {
      int m2 = tid;
      float2 w[16];
#pragma unroll
      for (int j = 0; j < 16; ++j) w[j] = sm64[(BR4[j] << 3) + m2];
      fft16(w);
#pragma unroll
      for (int k1 = 1; k1 < 16; ++k1) w[k1] = cmul(w[k1], tw[m2 * k1]);
#pragma unroll
      for (int k1 = 0; k1 < 16; ++k1) sm64[(k1 << 3) + m2] = w[k1];
    }
  }
  __syncthreads();

  // ---- col pass stage 2 + fftshift + amp/phase (+conjugate mirror writes)
  unsigned short* dst = feats + (size_t)b * IN_DIM + ch * 32768;
  {
    int col = tid & 63, t8 = tid >> 6;
    float2 u0[8], u1[8];
#pragma unroll
    for (int j = 0; j < 8; ++j) {
      u0[j] = tile[TIX((t8 << 3) + BR3[j], col)];
      u1[j] = tile[TIX(((t8 + 8) << 3) + BR3[j], col)];
    }
    fft8(u0);
    fft8(u1);
    const int ow = col + 64;
    const int owm = 64 - col;
#pragma unroll
    for (int k2 = 0; k2 < 8; ++k2) {
#pragma unroll
      for (int half = 0; half < 2; ++half) {
        float2 F = half ? u1[k2] : u0[k2];
        int kh = t8 + half * 8 + (k2 << 4);
        float amp = sqrtf(F.x * F.x + F.y * F.y);
        float ph = atan2f(F.y, F.x);
        int oh = kh ^ 64;
        dst[(oh << 7) + ow] = f2bf(amp);
        dst[16384 + (oh << 7) + ow] = f2bf(ph);
        if (col != 0) {
          int khm = (128 - kh) & 127;
          int ohm = khm ^ 64;
          dst[(ohm << 7) + owm] = f2bf(amp);
          dst[16384 + (ohm << 7) + owm] = f2bf(-ph);
        }
      }
    }
    if (tid < 8) {
      int t8t = tid;
      float2 e0[8], e1[8];
#pragma unroll
      for (int j = 0; j < 8; ++j) {
        e0[j] = sm64[(t8t << 3) + BR3[j]];
        e1[j] = sm64[((t8t + 8) << 3) + BR3[j]];
      }
      fft8(e0);
      fft8(e1);
#pragma unroll
      for (int k2 = 0; k2 < 8; ++k2) {
#pragma unroll
        for (int half = 0; half < 2; ++half) {
          float2 F = half ? e1[k2] : e0[k2];
          int kh = t8t + half * 8 + (k2 << 4);
          float amp = sqrtf(F.x * F.x + F.y * F.y);
          float ph = atan2f(F.y, F.x);
          int oh = kh ^ 64;
          dst[(oh << 7)] = f2bf(amp);
          dst[16384 + (oh << 7)] = f2bf(ph);
        }
      }
    }
  }
}

// ---------------------------------------------------------------------------
// Kernel 2: layer-1 GEMM. R9 tiling (MT=256, NT=128, S=64, grid 256 =
// 1 block/CU, 512 threads) but BK=64: each iteration processes TWO
// R9-style 32-wide sub-tiles under ONE barrier+wait set -> 24 iters
// instead of 48, halving per-iteration sync overhead at equal traffic.
// A: 3 bufs x 2 halves x 16KB (global_load_lds, staged 2 ahead).
// B: 2 bufs x 2 halves x 8KB (reg-staged fp32 -> bf16 once, ds_write).
// Per-wave VMEM ops/iter = 4 A + 4 B = 8.
// Waits: top vmcnt(8)+lgkmcnt(0); mid vmcnt(4) before writeB (forces
// A(k)+loadB(k), both issued >=1 iter prior); lgkmcnt(2) before MFMAs.
// ---------------------------------------------------------------------------
#define GS 64
#define GIT2 24

__global__ __launch_bounds__(512, 1) void gemm1_kernel(
    const unsigned short* __restrict__ feats, const float* __restrict__ W1,
    float* __restrict__ partial) {
  __shared__ __align__(16) unsigned short Asm[3][2][256 * 32];  // 96 KB
  __shared__ __align__(16) unsigned short Bsm[2][2][128 * 32];  // 32 KB
  const int tid = threadIdx.x;
  const int wv = tid >> 6, lane = tid & 63;

  const int f = blockIdx.x;
  const int xcd = f & 7, v = f >> 3;
  const int ks = xcd * 8 + (v & 7);   // 4 blocks sharing ks -> one XCD
  const int nt = v >> 3;
  const int n0 = nt * 128;
  const size_t k0 = (size_t)ks * 1536;

  const int al_row = lane >> 2;
  const int al_k = (lane & 3) * 8;
  const int brow = tid >> 2, bq = tid & 3;
  const float* bsrc = W1 + (size_t)(n0 + brow) * IN_DIM + k0 + bq * 8;

  // stage A tile `it` (64 k-wide, two 32-wide halves) into buffer buf
  auto stageA = [&](int buf, int it) {
    const size_t kb = k0 + (size_t)it * 64;
#pragma unroll
    for (int h = 0; h < 2; ++h) {
#pragma unroll
      for (int tl = 0; tl < 2; ++tl) {
        const int s = wv * 2 + tl;  // chunk 0..15 per half
        const unsigned short* ga =
            feats + (size_t)(s * 16 + al_row) * IN_DIM + kb + h * 32 + al_k;
        gload_lds16(ga, (char*)&Asm[buf][h][0] + s * 1024);
      }
    }
  };

  float4 br[2][2];  // [half][pair]
  auto loadB = [&](int it) {
#pragma unroll
    for (int h = 0; h < 2; ++h) {
      const float* p = bsrc + (size_t)it * 64 + h * 32;
      br[h][0] = *reinterpret_cast<const float4*>(p);
      br[h][1] = *reinterpret_cast<const float4*>(p + 4);
    }
  };
  auto writeB = [&](int buf) {
#pragma unroll
    for (int h = 0; h < 2; ++h) {
      u16x8 bw;
      bw[0] = f2bf(br[h][0].x); bw[1] = f2bf(br[h][0].y);
      bw[2] = f2bf(br[h][0].z); bw[3] = f2bf(br[h][0].w);
      bw[4] = f2bf(br[h][1].x); bw[5] = f2bf(br[h][1].y);
      bw[6] = f2bf(br[h][1].z); bw[7] = f2bf(br[h][1].w);
      *reinterpret_cast<u16x8*>(&Bsm[buf][h][brow * 32 + bq * 8]) = bw;
    }
  };

  f32x4 acc[4][4];
#pragma unroll
  for (int i = 0; i < 4; ++i)
#pragma unroll
    for (int jj = 0; jj < 4; ++jj) acc[i][jj] = (f32x4){0.f, 0.f, 0.f, 0.f};

  const int mr = wv & 3;   // 64-row M slice
  const int nc = wv >> 2;  // 64-col N slice
  const int rm = lane & 15, hi = lane >> 4;

  // prologue: A tiles 0,1 in flight; B tile 0 in LDS, tile 1 in regs.
  stageA(0, 0);
  stageA(1, 1);
  loadB(0);
  asm volatile("s_waitcnt vmcnt(0)" ::: "memory");
  writeB(0);
  loadB(1);

  int abuf = 0;  // k % 3, maintained by rotation
  for (int k = 0; k < GIT2; ++k) {
    const int rem = GIT2 - 1 - k;
    if (rem >= 1) {
      asm volatile("s_waitcnt vmcnt(8) lgkmcnt(0)" ::: "memory");
    } else {
      asm volatile("s_waitcnt vmcnt(0) lgkmcnt(0)" ::: "memory");
    }
    __builtin_amdgcn_sched_barrier(0);
    __builtin_amdgcn_s_barrier();
    __builtin_amdgcn_sched_barrier(0);

    const int bbuf = k & 1;
    bh8 afr[2][4], bfr[2][4];
#pragma unroll
    for (int h = 0; h < 2; ++h) {
#pragma unroll
      for (int i = 0; i < 4; ++i) {
        const int row = mr * 64 + i * 16 + rm;
        afr[h][i] =
            *reinterpret_cast<const bh8*>(&Asm[abuf][h][row * 32 + hi * 8]);
      }
#pragma unroll
      for (int jj = 0; jj < 4; ++jj) {
        const int row = nc * 64 + jj * 16 + rm;
        bfr[h][jj] =
            *reinterpret_cast<const bh8*>(&Bsm[bbuf][h][row * 32 + hi * 8]);
      }
    }
    __builtin_amdgcn_sched_barrier(0);

    // prefetch A tile k+2 into buffer (k+2)%3 == (k-1)%3 (read finished
    // by all waves before the barrier above)
    if (rem >= 2) {
      int sbuf = abuf + 2;
      if (sbuf >= 3) sbuf -= 3;
      stageA(sbuf, k + 2);
    }

    if (rem >= 1) {
      if (rem >= 2) {
        asm volatile("s_waitcnt vmcnt(4)" ::: "memory");
      } else {
        asm volatile("s_waitcnt vmcnt(0)" ::: "memory");
      }
      __builtin_amdgcn_sched_barrier(0);
      writeB((k + 1) & 1);
      if (rem >= 2) loadB(k + 2);
    }

    // frag ds_reads complete (the 2 ds_writes may stay outstanding)
    asm volatile("s_waitcnt lgkmcnt(2)" ::: "memory");
    __builtin_amdgcn_sched_barrier(0);

#pragma unroll
    for (int h = 0; h < 2; ++h)
#pragma unroll
      for (int i = 0; i < 4; ++i)
#pragma unroll
        for (int jj = 0; jj < 4; ++jj)
          acc[i][jj] = __builtin_amdgcn_mfma_f32_16x16x32_bf16(
              afr[h][i], bfr[h][jj], acc[i][jj], 0, 0, 0);

    abuf = (abuf == 2) ? 0 : abuf + 1;
  }

  // epilogue: C/D layout col=lane&15, row=(lane>>4)*4+reg (m89-verified)
  const int rg = lane >> 4;
  float* pbase = partial + ((size_t)ks << 17);
#pragma unroll
  for (int i = 0; i < 4; ++i) {
#pragma unroll
    for (int jj = 0; jj < 4; ++jj) {
      const int n = n0 + nc * 64 + jj * 16 + rm;
#pragma unroll
      for (int r = 0; r < 4; ++r) {
        const int m = mr * 64 + i * 16 + rg * 4 + r;
        pbase[((size_t)m << 9) + n] = acc[i][jj][r];
      }
    }
  }
}

// ---------------------------------------------------------------------------
// Kernel 3: FUSED tail (unchanged from R11).
// ---------------------------------------------------------------------------
__global__ __launch_bounds__(256) void tail_kernel(
    const float* __restrict__ partial, const float* __restrict__ b1,
    const float* __restrict__ W2, const float* __restrict__ b2,
    const float* __restrict__ W3, const float* __restrict__ b3,
    float* __restrict__ out) {
  __shared__ float x1s[512];
  __shared__ float x2s[256];
  const int b = blockIdx.x, n = threadIdx.x;

  {
    float s0 = b1[n], s1 = b1[n + 256];
    const float* pb = partial + ((size_t)b << 9);
#pragma unroll 8
    for (int p = 0; p < GS; ++p) {
      const float* pp = pb + ((size_t)p << 17);
      s0 += pp[n];
      s1 += pp[n + 256];
    }
    x1s[n] = fmaxf(s0, 0.f);
    x1s[n + 256] = fmaxf(s1, 0.f);
  }
  __syncthreads();

  {
    float acc = b2[n];
    const float* wr = W2 + (size_t)n * 512;
#pragma unroll 4
    for (int k = 0; k < 512; k += 4) {
      float4 w = *reinterpret_cast<const float4*>(wr + k);
      acc += x1s[k] * w.x + x1s[k + 1] * w.y + x1s[k + 2] * w.z + x1s[k + 3] * w.w;
    }
    x2s[n] = fmaxf(acc, 0.f);
  }
  __syncthreads();

  if (n < 128) {
    float acc = b3[n];
    const float* wr = W3 + (size_t)n * 256;
#pragma unroll 4
    for (int k = 0; k < 256; k += 4) {
      float4 w = *reinterpret_cast<const float4*>(wr + k);
      acc += x2s[k] * w.x + x2s[k + 1] * w.y + x2s[k + 2] * w.z + x2s[k + 3] * w.w;
    }
    out[b * 128 + n] = acc;
  }
}

extern "C" void kernel_launch(void* const* d_in, const int* in_sizes, int n_in,
                              void* d_out, int out_size, void* d_ws, size_t ws_size,
                              hipStream_t stream) {
  const float* img = (const float*)d_in[0];
  const float* W1 = (const float*)d_in[1];
  const float* b1 = (const float*)d_in[2];
  const float* W2 = (const float*)d_in[3];
  const float* b2 = (const float*)d_in[4];
  const float* W3 = (const float*)d_in[5];
  const float* b3 = (const float*)d_in[6];
  float* out = (float*)d_out;
  char* ws = (char*)d_ws;

  const size_t FEATS_B = 50331648ull;  // bf16 [256][98304]
  unsigned short* feats = (unsigned short*)ws;
  float* partial = (float*)(ws + FEATS_B);

  hipLaunchKernelGGL(fft_feats_kernel, dim3(3, 256), dim3(512), 0, stream, img, feats);
  hipLaunchKernelGGL(gemm1_kernel, dim3(256), dim3(512), 0, stream, feats, W1, partial);
  hipLaunchKernelGGL(tail_kernel, dim3(256), dim3(256), 0, stream,
                     partial, b1, W2, b2, W3, b3, out);
}